// Round 16
// baseline (118.225 us; speedup 1.0000x reference)
//
#include <hip/hip_runtime.h>
#include <hip/hip_cooperative_groups.h>

namespace cg = cooperative_groups;

// Problem constants
#define BB   8
#define CC   128
#define CR   16      // reduced channels = 128/8
#define HH   128
#define WW   128
#define HWSZ 16384   // 128*128
#define K2   9
#define NFRAG 72     // 8 ctiles * 9 taps

typedef _Float16 f16x8 __attribute__((ext_vector_type(8)));
typedef float    f32x4 __attribute__((ext_vector_type(4)));

// ws layout (float slots):
//   part  : [0, +16384)              per-tile {sum,sumsq} partials (f32)
//   tn_lo : [16384, +524288)         normalized t ch 0..7,  f16x8/pixel (b,hw)
//   tn_hi : [540672, +524288)        normalized t ch 8..15
//   afrag : [1064960, +18432)        A fragments f16x8/lane (bias at kk=16)
#define WS_PART  0
#define WS_TNLO  16384
#define WS_TNHI  540672
#define WS_AFRAG 1064960

// ONE cooperative kernel: phase 1 = conv1 (acc in regs) + part partials,
// blocks 512..529 = w2/b2 afrag prep; grid.sync(); phase 2 = stats
// re-reduce (L2-hot part) + normalize the IN-REGISTER acc -> tn planes.
// Raw t never touches memory.
__global__ __launch_bounds__(256) void k_pre(const float* __restrict__ x,
                                             const float* __restrict__ w1,
                                             const float* __restrict__ w2,
                                             const float* __restrict__ b2,
                                             const float* __restrict__ gamma,
                                             const float* __restrict__ beta,
                                             float* __restrict__ ws) {
    const int bid = blockIdx.x;
    const int tid = threadIdx.x;
    cg::grid_group grid = cg::this_grid();

    if (bid >= 512) {   // ---- prep branch ----
        const int id = (bid - 512) * 256 + tid;
        if (id < NFRAG * 64) {
            const int lane = id & 63;
            const int frag = id >> 6;           // ct*9 + k
            const int ct = frag / 9, k = frag - ct * 9;
            const int row = lane & 15, lg = lane >> 4;
            f16x8 v;
#pragma unroll
            for (int i = 0; i < 8; ++i) {
                const int kk = lg * 8 + i;
                float w = 0.f;
                if (kk < CR)        w = w2[(size_t)((ct * 16 + row) * K2 + k) * CR + kk];
                else if (kk == CR)  w = b2[(ct * 16 + row) * K2 + k];
                v[i] = (_Float16)w;
            }
            ((f16x8*)(ws + WS_AFRAG))[frag * 64 + lane] = v;
        }
        grid.sync();
        return;
    }

    // ---- phase 1: conv1 ----
    const int tile = bid & 63;
    const int b    = bid >> 6;
    const int pix  = tile * 256 + tid;

    // w1 staged TRANSPOSED: w1s[cin*16 + o] -> per-cin weights are f32x4 quads
    __shared__ float w1s[CR * CC];   // 8 KB
    for (int i = tid; i < CR * CC; i += 256)
        w1s[i] = w1[(i & 15) * CC + (i >> 4)];
    __syncthreads();

    const float* xb = x + (size_t)b * CC * HWSZ + pix;
    float acc[CR];
#pragma unroll
    for (int o = 0; o < CR; ++o) acc[o] = 0.f;

#pragma unroll 1
    for (int c0 = 0; c0 < CC; c0 += 16) {
        float xv[16];
#pragma unroll
        for (int u = 0; u < 16; ++u)
            xv[u] = xb[(size_t)(c0 + u) * HWSZ];
#pragma unroll
        for (int u = 0; u < 16; ++u) {
            const f32x4* wv4 = (const f32x4*)&w1s[(c0 + u) * CR];  // wave-uniform
            const f32x4 wa = wv4[0], wb = wv4[1], wc = wv4[2], wd = wv4[3];
#pragma unroll
            for (int j = 0; j < 4; ++j) {
                acc[j]      = fmaf(wa[j], xv[u], acc[j]);
                acc[4 + j]  = fmaf(wb[j], xv[u], acc[4 + j]);
                acc[8 + j]  = fmaf(wc[j], xv[u], acc[8 + j]);
                acc[12 + j] = fmaf(wd[j], xv[u], acc[12 + j]);
            }
        }
    }

    // per-tile {sum, sumsq} partials
    __shared__ float red[4][CR][2];
    {
        const int lane = tid & 63;
        const int wv   = tid >> 6;
#pragma unroll
        for (int o = 0; o < CR; ++o) {
            float s = acc[o];
            float q = s * s;
#pragma unroll
            for (int off = 32; off > 0; off >>= 1) {
                s += __shfl_down(s, off, 64);
                q += __shfl_down(q, off, 64);
            }
            if (lane == 0) { red[wv][o][0] = s; red[wv][o][1] = q; }
        }
        __syncthreads();
        if (tid < CR) {
            const int o = tid;
            float s = red[0][o][0] + red[1][o][0] + red[2][o][0] + red[3][o][0];
            float q = red[0][o][1] + red[1][o][1] + red[2][o][1] + red[3][o][1];
            const int blk = b * 64 + tile;
            ws[WS_PART + blk * 32 + o * 2 + 0] = s;
            ws[WS_PART + blk * 32 + o * 2 + 1] = q;
        }
    }

    // ---- all blocks rendezvous; part[] now globally visible ----
    grid.sync();

    // ---- phase 2: stats + normalize the in-register acc ----
    __shared__ float sts[CR][2];
    {
        const int o  = tid >> 4;
        const int t4 = tid & 15;
        float s = 0.f, q = 0.f;
#pragma unroll
        for (int j = 0; j < 4; ++j) {
            const int blk = b * 64 + t4 + j * 16;
            s += ws[WS_PART + blk * 32 + o * 2 + 0];
            q += ws[WS_PART + blk * 32 + o * 2 + 1];
        }
#pragma unroll
        for (int off = 8; off > 0; off >>= 1) {
            s += __shfl_down(s, off, 16);
            q += __shfl_down(q, off, 16);
        }
        if (t4 == 0) {
            const float mean = s * (1.f / (float)HWSZ);
            const float var  = q * (1.f / (float)HWSZ) - mean * mean;
            const float rstd = rsqrtf(var + 1e-5f);
            const float sc   = gamma[o] * rstd;
            sts[o][0] = sc;
            sts[o][1] = beta[o] - mean * sc;
        }
    }
    __syncthreads();

    const int p = b * HWSZ + pix;   // == bid*256+tid
    f16x8 nlo, nhi;
#pragma unroll
    for (int i = 0; i < 8; ++i) {
        float v0 = fmaf(acc[i],     sts[i][0],     sts[i][1]);
        float v1 = fmaf(acc[i + 8], sts[i + 8][0], sts[i + 8][1]);
        nlo[i] = (_Float16)(v0 > 0.f ? v0 : 0.f);
        nhi[i] = (_Float16)(v1 > 0.f ? v1 : 0.f);
    }
    ((f16x8*)(ws + WS_TNLO))[p] = nlo;
    ((f16x8*)(ws + WS_TNHI))[p] = nhi;
}

// Fused MFMA weight-gen + dilated 3x3 involution apply — EXACT r12 body
// (best measured: 43.3-43.6 us). No LDS/barriers; 9 reg A-frags; 4 x-group
// sweep with rotation prefetch of next B-fragment; NT stores for out.
// grid = 4096, XCD-chunked swizzle, y innermost for L2 tap locality.
__global__ __launch_bounds__(256) void k_main(const float* __restrict__ x,
                                              const float* __restrict__ ws,
                                              float* __restrict__ out) {
    const int bid = blockIdx.x;                 // 0..4095
    const int w   = (bid & 7) * 512 + (bid >> 3);
    const int y4    = w & 31;
    const int xhalf = (w >> 5) & 1;
    const int ct    = (w >> 6) & 7;
    const int b     = w >> 9;

    const int tid  = threadIdx.x;
    const int wv   = tid >> 6;
    const int lane = tid & 63;
    const int lg   = lane >> 4;           // 0..3
    const int ln   = lane & 15;
    const int y    = y4 * 4 + wv;

    // B-fragment plane for this lane group (lg0 -> lo, lg1 -> hi)
    const f16x8* tp = (const f16x8*)(ws + (lg == 1 ? WS_TNHI : WS_TNLO))
                      + ((size_t)b << 14);
    const int tbase = y * WW + xhalf * 64 + ln;

    // issue first tnf load before the af loads so it overlaps them
    f16x8 tnf = {}, tnf_nxt = {};
    if (lg < 2)  tnf = tp[tbase];
    if (lg == 2) tnf[0] = (_Float16)1.f;

    // ---- 9 A-fragments into registers (L2-hot ws reads, once per wave) ----
    const f16x8* afr = (const f16x8*)(ws + WS_AFRAG) + (size_t)ct * K2 * 64 + lane;
    f16x8 af[K2];
#pragma unroll
    for (int k = 0; k < K2; ++k) af[k] = afr[k * 64];

    const int crow = lg * 4;
    const int cb   = ct * 16 + crow;
    const float* xp = x   + ((size_t)b * CC + cb) * HWSZ;
    float*       op = out + ((size_t)b * CC + cb) * HWSZ;
    const bool yint = (y >= 2) && (y < HH - 2);
    const f32x4 zc = {0.f, 0.f, 0.f, 0.f};

#pragma unroll 1
    for (int g = 0; g < 4; ++g) {
        const int colb = xhalf * 64 + g * 16;
        const int col  = colb + ln;
        const int pix  = y * WW + col;

        // prefetch next group's B-fragment (hides L2 latency under compute)
        if (g < 3 && lg < 2)
            tnf_nxt = tp[tbase + (g + 1) * 16];

        f32x4 acc = {0.f, 0.f, 0.f, 0.f};
        const bool xint = (colb >= 2) && (colb + 17 < WW);

        if (yint && xint) {
            const float* q0 = xp + pix;
            const float* q1 = q0 + HWSZ;
            const float* q2 = q0 + 2 * HWSZ;
            const float* q3 = q0 + 3 * HWSZ;
#pragma unroll
            for (int k = 0; k < K2; ++k) {
                const int d = ((k / 3) * 2 - 2) * WW + ((k % 3) * 2 - 2);  // compile-time imm
                const f32x4 wg = __builtin_amdgcn_mfma_f32_16x16x32_f16(af[k], tnf, zc, 0, 0, 0);
                acc[0] = fmaf(wg[0], q0[d], acc[0]);
                acc[1] = fmaf(wg[1], q1[d], acc[1]);
                acc[2] = fmaf(wg[2], q2[d], acc[2]);
                acc[3] = fmaf(wg[3], q3[d], acc[3]);
            }
        } else {
            int  xoff[3];
            bool xm[3];
#pragma unroll
            for (int j = 0; j < 3; ++j) {
                const int xx = col + (j * 2 - 2);
                xm[j]   = ((unsigned)xx < (unsigned)WW);
                xoff[j] = xx & (WW - 1);
            }
#pragma unroll
            for (int k = 0; k < K2; ++k) {
                const int yy  = y + ((k / 3) * 2 - 2);
                const int off = ((yy & (HH - 1)) << 7) + xoff[k % 3];
                const float m = (xm[k % 3] && ((unsigned)yy < (unsigned)HH)) ? 1.f : 0.f;
                const f32x4 wg = __builtin_amdgcn_mfma_f32_16x16x32_f16(af[k], tnf, zc, 0, 0, 0);
                acc[0] = fmaf(wg[0], xp[off + 0 * HWSZ] * m, acc[0]);
                acc[1] = fmaf(wg[1], xp[off + 1 * HWSZ] * m, acc[1]);
                acc[2] = fmaf(wg[2], xp[off + 2 * HWSZ] * m, acc[2]);
                acc[3] = fmaf(wg[3], xp[off + 3 * HWSZ] * m, acc[3]);
            }
        }

        float* o = op + pix;
        __builtin_nontemporal_store(acc[0], o + 0 * HWSZ);
        __builtin_nontemporal_store(acc[1], o + 1 * HWSZ);
        __builtin_nontemporal_store(acc[2], o + 2 * HWSZ);
        __builtin_nontemporal_store(acc[3], o + 3 * HWSZ);

        tnf = tnf_nxt;
        if (lg == 2) tnf[0] = (_Float16)1.f;   // restore bias lane (reg move)
    }
}

extern "C" void kernel_launch(void* const* d_in, const int* in_sizes, int n_in,
                              void* d_out, int out_size, void* d_ws, size_t ws_size,
                              hipStream_t stream) {
    const float* x     = (const float*)d_in[0];
    const float* w1    = (const float*)d_in[1];
    const float* gamma = (const float*)d_in[2];
    const float* beta  = (const float*)d_in[3];
    const float* w2    = (const float*)d_in[4];
    const float* b2    = (const float*)d_in[5];
    float* out = (float*)d_out;
    float* ws  = (float*)d_ws;

    void* args[7] = {(void*)&x, (void*)&w1, (void*)&w2, (void*)&b2,
                     (void*)&gamma, (void*)&beta, (void*)&ws};
    hipLaunchCooperativeKernel((const void*)k_pre, dim3(530), dim3(256),
                               args, 0, stream);

    k_main<<<4096, 256, 0, stream>>>(x, ws, out);
}

// Round 17
// 117.724 us; speedup vs baseline: 1.0043x; 1.0043x over previous
//
#include <hip/hip_runtime.h>
#include <hip/hip_cooperative_groups.h>

namespace cg = cooperative_groups;

// Problem constants
#define BB   8
#define CC   128
#define CR   16      // reduced channels = 128/8
#define HH   128
#define WW   128
#define HWSZ 16384   // 128*128
#define K2   9
#define NFRAG 72     // 8 ctiles * 9 taps

typedef _Float16 f16x8 __attribute__((ext_vector_type(8)));
typedef float    f32x4 __attribute__((ext_vector_type(4)));

// ws layout (float slots):
//   part  : [0, +16384)              per-tile {sum,sumsq} partials (f32)
//   tn_lo : [16384, +524288)         normalized t ch 0..7,  f16x8/pixel (b,hw)
//   tn_hi : [540672, +524288)        normalized t ch 8..15
//   afrag : [1064960, +18432)        A fragments f16x8/lane (bias at kk=16)
#define WS_PART  0
#define WS_TNLO  16384
#define WS_TNHI  540672
#define WS_AFRAG 1064960

// ONE cooperative kernel: phase 1 = conv1 (acc in regs) + part partials,
// blocks 512..529 = w2/b2 afrag prep; grid.sync(); phase 2 = stats
// re-reduce (L2-hot part) + normalize the IN-REGISTER acc -> tn planes.
// Raw t never touches memory.
__global__ __launch_bounds__(256) void k_pre(const float* __restrict__ x,
                                             const float* __restrict__ w1,
                                             const float* __restrict__ w2,
                                             const float* __restrict__ b2,
                                             const float* __restrict__ gamma,
                                             const float* __restrict__ beta,
                                             float* __restrict__ ws) {
    const int bid = blockIdx.x;
    const int tid = threadIdx.x;
    cg::grid_group grid = cg::this_grid();

    if (bid >= 512) {   // ---- prep branch ----
        const int id = (bid - 512) * 256 + tid;
        if (id < NFRAG * 64) {
            const int lane = id & 63;
            const int frag = id >> 6;           // ct*9 + k
            const int ct = frag / 9, k = frag - ct * 9;
            const int row = lane & 15, lg = lane >> 4;
            f16x8 v;
#pragma unroll
            for (int i = 0; i < 8; ++i) {
                const int kk = lg * 8 + i;
                float w = 0.f;
                if (kk < CR)        w = w2[(size_t)((ct * 16 + row) * K2 + k) * CR + kk];
                else if (kk == CR)  w = b2[(ct * 16 + row) * K2 + k];
                v[i] = (_Float16)w;
            }
            ((f16x8*)(ws + WS_AFRAG))[frag * 64 + lane] = v;
        }
        grid.sync();
        return;
    }

    // ---- phase 1: conv1 ----
    const int tile = bid & 63;
    const int b    = bid >> 6;
    const int pix  = tile * 256 + tid;

    // w1 staged TRANSPOSED: w1s[cin*16 + o] -> per-cin weights are f32x4 quads
    __shared__ float w1s[CR * CC];   // 8 KB
    for (int i = tid; i < CR * CC; i += 256)
        w1s[i] = w1[(i & 15) * CC + (i >> 4)];
    __syncthreads();

    const float* xb = x + (size_t)b * CC * HWSZ + pix;
    float acc[CR];
#pragma unroll
    for (int o = 0; o < CR; ++o) acc[o] = 0.f;

#pragma unroll 1
    for (int c0 = 0; c0 < CC; c0 += 16) {
        float xv[16];
#pragma unroll
        for (int u = 0; u < 16; ++u)
            xv[u] = xb[(size_t)(c0 + u) * HWSZ];
#pragma unroll
        for (int u = 0; u < 16; ++u) {
            const f32x4* wv4 = (const f32x4*)&w1s[(c0 + u) * CR];  // wave-uniform
            const f32x4 wa = wv4[0], wb = wv4[1], wc = wv4[2], wd = wv4[3];
#pragma unroll
            for (int j = 0; j < 4; ++j) {
                acc[j]      = fmaf(wa[j], xv[u], acc[j]);
                acc[4 + j]  = fmaf(wb[j], xv[u], acc[4 + j]);
                acc[8 + j]  = fmaf(wc[j], xv[u], acc[8 + j]);
                acc[12 + j] = fmaf(wd[j], xv[u], acc[12 + j]);
            }
        }
    }

    // per-tile {sum, sumsq} partials
    __shared__ float red[4][CR][2];
    {
        const int lane = tid & 63;
        const int wv   = tid >> 6;
#pragma unroll
        for (int o = 0; o < CR; ++o) {
            float s = acc[o];
            float q = s * s;
#pragma unroll
            for (int off = 32; off > 0; off >>= 1) {
                s += __shfl_down(s, off, 64);
                q += __shfl_down(q, off, 64);
            }
            if (lane == 0) { red[wv][o][0] = s; red[wv][o][1] = q; }
        }
        __syncthreads();
        if (tid < CR) {
            const int o = tid;
            float s = red[0][o][0] + red[1][o][0] + red[2][o][0] + red[3][o][0];
            float q = red[0][o][1] + red[1][o][1] + red[2][o][1] + red[3][o][1];
            const int blk = b * 64 + tile;
            ws[WS_PART + blk * 32 + o * 2 + 0] = s;
            ws[WS_PART + blk * 32 + o * 2 + 1] = q;
        }
    }

    // ---- all blocks rendezvous; part[] now globally visible ----
    grid.sync();

    // ---- phase 2: stats + normalize the in-register acc ----
    __shared__ float sts[CR][2];
    {
        const int o  = tid >> 4;
        const int t4 = tid & 15;
        float s = 0.f, q = 0.f;
#pragma unroll
        for (int j = 0; j < 4; ++j) {
            const int blk = b * 64 + t4 + j * 16;
            s += ws[WS_PART + blk * 32 + o * 2 + 0];
            q += ws[WS_PART + blk * 32 + o * 2 + 1];
        }
#pragma unroll
        for (int off = 8; off > 0; off >>= 1) {
            s += __shfl_down(s, off, 16);
            q += __shfl_down(q, off, 16);
        }
        if (t4 == 0) {
            const float mean = s * (1.f / (float)HWSZ);
            const float var  = q * (1.f / (float)HWSZ) - mean * mean;
            const float rstd = rsqrtf(var + 1e-5f);
            const float sc   = gamma[o] * rstd;
            sts[o][0] = sc;
            sts[o][1] = beta[o] - mean * sc;
        }
    }
    __syncthreads();

    const int p = b * HWSZ + pix;   // == bid*256+tid
    f16x8 nlo, nhi;
#pragma unroll
    for (int i = 0; i < 8; ++i) {
        float v0 = fmaf(acc[i],     sts[i][0],     sts[i][1]);
        float v1 = fmaf(acc[i + 8], sts[i + 8][0], sts[i + 8][1]);
        nlo[i] = (_Float16)(v0 > 0.f ? v0 : 0.f);
        nhi[i] = (_Float16)(v1 > 0.f ? v1 : 0.f);
    }
    ((f16x8*)(ws + WS_TNLO))[p] = nlo;
    ((f16x8*)(ws + WS_TNHI))[p] = nhi;
}

// Fused MFMA weight-gen + dilated 3x3 involution apply — EXACT r12 body
// (best measured: 43.3-43.6 us). No LDS/barriers; 9 reg A-frags; 4 x-group
// sweep with rotation prefetch of next B-fragment; NT stores for out.
// grid = 4096, XCD-chunked swizzle, y innermost for L2 tap locality.
__global__ __launch_bounds__(256) void k_main(const float* __restrict__ x,
                                              const float* __restrict__ ws,
                                              float* __restrict__ out) {
    const int bid = blockIdx.x;                 // 0..4095
    const int w   = (bid & 7) * 512 + (bid >> 3);
    const int y4    = w & 31;
    const int xhalf = (w >> 5) & 1;
    const int ct    = (w >> 6) & 7;
    const int b     = w >> 9;

    const int tid  = threadIdx.x;
    const int wv   = tid >> 6;
    const int lane = tid & 63;
    const int lg   = lane >> 4;           // 0..3
    const int ln   = lane & 15;
    const int y    = y4 * 4 + wv;

    // B-fragment plane for this lane group (lg0 -> lo, lg1 -> hi)
    const f16x8* tp = (const f16x8*)(ws + (lg == 1 ? WS_TNHI : WS_TNLO))
                      + ((size_t)b << 14);
    const int tbase = y * WW + xhalf * 64 + ln;

    // issue first tnf load before the af loads so it overlaps them
    f16x8 tnf = {}, tnf_nxt = {};
    if (lg < 2)  tnf = tp[tbase];
    if (lg == 2) tnf[0] = (_Float16)1.f;

    // ---- 9 A-fragments into registers (L2-hot ws reads, once per wave) ----
    const f16x8* afr = (const f16x8*)(ws + WS_AFRAG) + (size_t)ct * K2 * 64 + lane;
    f16x8 af[K2];
#pragma unroll
    for (int k = 0; k < K2; ++k) af[k] = afr[k * 64];

    const int crow = lg * 4;
    const int cb   = ct * 16 + crow;
    const float* xp = x   + ((size_t)b * CC + cb) * HWSZ;
    float*       op = out + ((size_t)b * CC + cb) * HWSZ;
    const bool yint = (y >= 2) && (y < HH - 2);
    const f32x4 zc = {0.f, 0.f, 0.f, 0.f};

#pragma unroll 1
    for (int g = 0; g < 4; ++g) {
        const int colb = xhalf * 64 + g * 16;
        const int col  = colb + ln;
        const int pix  = y * WW + col;

        // prefetch next group's B-fragment (hides L2 latency under compute)
        if (g < 3 && lg < 2)
            tnf_nxt = tp[tbase + (g + 1) * 16];

        f32x4 acc = {0.f, 0.f, 0.f, 0.f};
        const bool xint = (colb >= 2) && (colb + 17 < WW);

        if (yint && xint) {
            const float* q0 = xp + pix;
            const float* q1 = q0 + HWSZ;
            const float* q2 = q0 + 2 * HWSZ;
            const float* q3 = q0 + 3 * HWSZ;
#pragma unroll
            for (int k = 0; k < K2; ++k) {
                const int d = ((k / 3) * 2 - 2) * WW + ((k % 3) * 2 - 2);  // compile-time imm
                const f32x4 wg = __builtin_amdgcn_mfma_f32_16x16x32_f16(af[k], tnf, zc, 0, 0, 0);
                acc[0] = fmaf(wg[0], q0[d], acc[0]);
                acc[1] = fmaf(wg[1], q1[d], acc[1]);
                acc[2] = fmaf(wg[2], q2[d], acc[2]);
                acc[3] = fmaf(wg[3], q3[d], acc[3]);
            }
        } else {
            int  xoff[3];
            bool xm[3];
#pragma unroll
            for (int j = 0; j < 3; ++j) {
                const int xx = col + (j * 2 - 2);
                xm[j]   = ((unsigned)xx < (unsigned)WW);
                xoff[j] = xx & (WW - 1);
            }
#pragma unroll
            for (int k = 0; k < K2; ++k) {
                const int yy  = y + ((k / 3) * 2 - 2);
                const int off = ((yy & (HH - 1)) << 7) + xoff[k % 3];
                const float m = (xm[k % 3] && ((unsigned)yy < (unsigned)HH)) ? 1.f : 0.f;
                const f32x4 wg = __builtin_amdgcn_mfma_f32_16x16x32_f16(af[k], tnf, zc, 0, 0, 0);
                acc[0] = fmaf(wg[0], xp[off + 0 * HWSZ] * m, acc[0]);
                acc[1] = fmaf(wg[1], xp[off + 1 * HWSZ] * m, acc[1]);
                acc[2] = fmaf(wg[2], xp[off + 2 * HWSZ] * m, acc[2]);
                acc[3] = fmaf(wg[3], xp[off + 3 * HWSZ] * m, acc[3]);
            }
        }

        float* o = op + pix;
        __builtin_nontemporal_store(acc[0], o + 0 * HWSZ);
        __builtin_nontemporal_store(acc[1], o + 1 * HWSZ);
        __builtin_nontemporal_store(acc[2], o + 2 * HWSZ);
        __builtin_nontemporal_store(acc[3], o + 3 * HWSZ);

        tnf = tnf_nxt;
        if (lg == 2) tnf[0] = (_Float16)1.f;   // restore bias lane (reg move)
    }
}

extern "C" void kernel_launch(void* const* d_in, const int* in_sizes, int n_in,
                              void* d_out, int out_size, void* d_ws, size_t ws_size,
                              hipStream_t stream) {
    const float* x     = (const float*)d_in[0];
    const float* w1    = (const float*)d_in[1];
    const float* gamma = (const float*)d_in[2];
    const float* beta  = (const float*)d_in[3];
    const float* w2    = (const float*)d_in[4];
    const float* b2    = (const float*)d_in[5];
    float* out = (float*)d_out;
    float* ws  = (float*)d_ws;

    void* args[7] = {(void*)&x, (void*)&w1, (void*)&w2, (void*)&b2,
                     (void*)&gamma, (void*)&beta, (void*)&ws};
    hipLaunchCooperativeKernel((const void*)k_pre, dim3(530), dim3(256),
                               args, 0, stream);

    k_main<<<4096, 256, 0, stream>>>(x, ws, out);
}

// Round 18
// 116.951 us; speedup vs baseline: 1.0109x; 1.0066x over previous
//
#include <hip/hip_runtime.h>
#include <hip/hip_cooperative_groups.h>

namespace cg = cooperative_groups;

// Problem constants
#define BB   8
#define CC   128
#define CR   16      // reduced channels = 128/8
#define HH   128
#define WW   128
#define HWSZ 16384   // 128*128
#define K2   9
#define NFRAG 72     // 8 ctiles * 9 taps

typedef _Float16 f16x8 __attribute__((ext_vector_type(8)));
typedef float    f32x4 __attribute__((ext_vector_type(4)));

// ws layout (float slots):
//   part  : [0, +16384)              per-tile {sum,sumsq} partials (f32)
//   tn_lo : [16384, +524288)         normalized t ch 0..7,  f16x8/pixel (b,hw)
//   tn_hi : [540672, +524288)        normalized t ch 8..15
//   afrag : [1064960, +18432)        A fragments f16x8/lane (bias at kk=16)
#define WS_PART  0
#define WS_TNLO  16384
#define WS_TNHI  540672
#define WS_AFRAG 1064960

// ONE cooperative kernel: phase 1 = conv1 (acc in regs) + part partials,
// blocks 512..529 = w2/b2 afrag prep; grid.sync(); phase 2 = stats
// re-reduce (L2-hot part) + normalize the IN-REGISTER acc -> tn planes.
// Raw t never touches memory.
__global__ __launch_bounds__(256) void k_pre(const float* __restrict__ x,
                                             const float* __restrict__ w1,
                                             const float* __restrict__ w2,
                                             const float* __restrict__ b2,
                                             const float* __restrict__ gamma,
                                             const float* __restrict__ beta,
                                             float* __restrict__ ws) {
    const int bid = blockIdx.x;
    const int tid = threadIdx.x;
    cg::grid_group grid = cg::this_grid();

    if (bid >= 512) {   // ---- prep branch ----
        const int id = (bid - 512) * 256 + tid;
        if (id < NFRAG * 64) {
            const int lane = id & 63;
            const int frag = id >> 6;           // ct*9 + k
            const int ct = frag / 9, k = frag - ct * 9;
            const int row = lane & 15, lg = lane >> 4;
            f16x8 v;
#pragma unroll
            for (int i = 0; i < 8; ++i) {
                const int kk = lg * 8 + i;
                float w = 0.f;
                if (kk < CR)        w = w2[(size_t)((ct * 16 + row) * K2 + k) * CR + kk];
                else if (kk == CR)  w = b2[(ct * 16 + row) * K2 + k];
                v[i] = (_Float16)w;
            }
            ((f16x8*)(ws + WS_AFRAG))[frag * 64 + lane] = v;
        }
        grid.sync();
        return;
    }

    // ---- phase 1: conv1 ----
    const int tile = bid & 63;
    const int b    = bid >> 6;
    const int pix  = tile * 256 + tid;

    // w1 staged TRANSPOSED: w1s[cin*16 + o] -> per-cin weights are f32x4 quads
    __shared__ float w1s[CR * CC];   // 8 KB
    for (int i = tid; i < CR * CC; i += 256)
        w1s[i] = w1[(i & 15) * CC + (i >> 4)];
    __syncthreads();

    const float* xb = x + (size_t)b * CC * HWSZ + pix;
    float acc[CR];
#pragma unroll
    for (int o = 0; o < CR; ++o) acc[o] = 0.f;

#pragma unroll 1
    for (int c0 = 0; c0 < CC; c0 += 16) {
        float xv[16];
#pragma unroll
        for (int u = 0; u < 16; ++u)
            xv[u] = xb[(size_t)(c0 + u) * HWSZ];
#pragma unroll
        for (int u = 0; u < 16; ++u) {
            const f32x4* wv4 = (const f32x4*)&w1s[(c0 + u) * CR];  // wave-uniform
            const f32x4 wa = wv4[0], wb = wv4[1], wc = wv4[2], wd = wv4[3];
#pragma unroll
            for (int j = 0; j < 4; ++j) {
                acc[j]      = fmaf(wa[j], xv[u], acc[j]);
                acc[4 + j]  = fmaf(wb[j], xv[u], acc[4 + j]);
                acc[8 + j]  = fmaf(wc[j], xv[u], acc[8 + j]);
                acc[12 + j] = fmaf(wd[j], xv[u], acc[12 + j]);
            }
        }
    }

    // per-tile {sum, sumsq} partials
    __shared__ float red[4][CR][2];
    {
        const int lane = tid & 63;
        const int wv   = tid >> 6;
#pragma unroll
        for (int o = 0; o < CR; ++o) {
            float s = acc[o];
            float q = s * s;
#pragma unroll
            for (int off = 32; off > 0; off >>= 1) {
                s += __shfl_down(s, off, 64);
                q += __shfl_down(q, off, 64);
            }
            if (lane == 0) { red[wv][o][0] = s; red[wv][o][1] = q; }
        }
        __syncthreads();
        if (tid < CR) {
            const int o = tid;
            float s = red[0][o][0] + red[1][o][0] + red[2][o][0] + red[3][o][0];
            float q = red[0][o][1] + red[1][o][1] + red[2][o][1] + red[3][o][1];
            const int blk = b * 64 + tile;
            ws[WS_PART + blk * 32 + o * 2 + 0] = s;
            ws[WS_PART + blk * 32 + o * 2 + 1] = q;
        }
    }

    // ---- all blocks rendezvous; part[] now globally visible ----
    grid.sync();

    // ---- phase 2: stats + normalize the in-register acc ----
    __shared__ float sts[CR][2];
    {
        const int o  = tid >> 4;
        const int t4 = tid & 15;
        float s = 0.f, q = 0.f;
#pragma unroll
        for (int j = 0; j < 4; ++j) {
            const int blk = b * 64 + t4 + j * 16;
            s += ws[WS_PART + blk * 32 + o * 2 + 0];
            q += ws[WS_PART + blk * 32 + o * 2 + 1];
        }
#pragma unroll
        for (int off = 8; off > 0; off >>= 1) {
            s += __shfl_down(s, off, 16);
            q += __shfl_down(q, off, 16);
        }
        if (t4 == 0) {
            const float mean = s * (1.f / (float)HWSZ);
            const float var  = q * (1.f / (float)HWSZ) - mean * mean;
            const float rstd = rsqrtf(var + 1e-5f);
            const float sc   = gamma[o] * rstd;
            sts[o][0] = sc;
            sts[o][1] = beta[o] - mean * sc;
        }
    }
    __syncthreads();

    const int p = b * HWSZ + pix;   // == bid*256+tid
    f16x8 nlo, nhi;
#pragma unroll
    for (int i = 0; i < 8; ++i) {
        float v0 = fmaf(acc[i],     sts[i][0],     sts[i][1]);
        float v1 = fmaf(acc[i + 8], sts[i + 8][0], sts[i + 8][1]);
        nlo[i] = (_Float16)(v0 > 0.f ? v0 : 0.f);
        nhi[i] = (_Float16)(v1 > 0.f ? v1 : 0.f);
    }
    ((f16x8*)(ws + WS_TNLO))[p] = nlo;
    ((f16x8*)(ws + WS_TNHI))[p] = nhi;
}

// Fused MFMA weight-gen + dilated 3x3 involution apply — EXACT r12 body
// (best measured: 43.3-43.6 us). No LDS/barriers; 9 reg A-frags; 4 x-group
// sweep with rotation prefetch of next B-fragment; NT stores for out.
// grid = 4096, XCD-chunked swizzle, y innermost for L2 tap locality.
__global__ __launch_bounds__(256) void k_main(const float* __restrict__ x,
                                              const float* __restrict__ ws,
                                              float* __restrict__ out) {
    const int bid = blockIdx.x;                 // 0..4095
    const int w   = (bid & 7) * 512 + (bid >> 3);
    const int y4    = w & 31;
    const int xhalf = (w >> 5) & 1;
    const int ct    = (w >> 6) & 7;
    const int b     = w >> 9;

    const int tid  = threadIdx.x;
    const int wv   = tid >> 6;
    const int lane = tid & 63;
    const int lg   = lane >> 4;           // 0..3
    const int ln   = lane & 15;
    const int y    = y4 * 4 + wv;

    // B-fragment plane for this lane group (lg0 -> lo, lg1 -> hi)
    const f16x8* tp = (const f16x8*)(ws + (lg == 1 ? WS_TNHI : WS_TNLO))
                      + ((size_t)b << 14);
    const int tbase = y * WW + xhalf * 64 + ln;

    // issue first tnf load before the af loads so it overlaps them
    f16x8 tnf = {}, tnf_nxt = {};
    if (lg < 2)  tnf = tp[tbase];
    if (lg == 2) tnf[0] = (_Float16)1.f;

    // ---- 9 A-fragments into registers (L2-hot ws reads, once per wave) ----
    const f16x8* afr = (const f16x8*)(ws + WS_AFRAG) + (size_t)ct * K2 * 64 + lane;
    f16x8 af[K2];
#pragma unroll
    for (int k = 0; k < K2; ++k) af[k] = afr[k * 64];

    const int crow = lg * 4;
    const int cb   = ct * 16 + crow;
    const float* xp = x   + ((size_t)b * CC + cb) * HWSZ;
    float*       op = out + ((size_t)b * CC + cb) * HWSZ;
    const bool yint = (y >= 2) && (y < HH - 2);
    const f32x4 zc = {0.f, 0.f, 0.f, 0.f};

#pragma unroll 1
    for (int g = 0; g < 4; ++g) {
        const int colb = xhalf * 64 + g * 16;
        const int col  = colb + ln;
        const int pix  = y * WW + col;

        // prefetch next group's B-fragment (hides L2 latency under compute)
        if (g < 3 && lg < 2)
            tnf_nxt = tp[tbase + (g + 1) * 16];

        f32x4 acc = {0.f, 0.f, 0.f, 0.f};
        const bool xint = (colb >= 2) && (colb + 17 < WW);

        if (yint && xint) {
            const float* q0 = xp + pix;
            const float* q1 = q0 + HWSZ;
            const float* q2 = q0 + 2 * HWSZ;
            const float* q3 = q0 + 3 * HWSZ;
#pragma unroll
            for (int k = 0; k < K2; ++k) {
                const int d = ((k / 3) * 2 - 2) * WW + ((k % 3) * 2 - 2);  // compile-time imm
                const f32x4 wg = __builtin_amdgcn_mfma_f32_16x16x32_f16(af[k], tnf, zc, 0, 0, 0);
                acc[0] = fmaf(wg[0], q0[d], acc[0]);
                acc[1] = fmaf(wg[1], q1[d], acc[1]);
                acc[2] = fmaf(wg[2], q2[d], acc[2]);
                acc[3] = fmaf(wg[3], q3[d], acc[3]);
            }
        } else {
            int  xoff[3];
            bool xm[3];
#pragma unroll
            for (int j = 0; j < 3; ++j) {
                const int xx = col + (j * 2 - 2);
                xm[j]   = ((unsigned)xx < (unsigned)WW);
                xoff[j] = xx & (WW - 1);
            }
#pragma unroll
            for (int k = 0; k < K2; ++k) {
                const int yy  = y + ((k / 3) * 2 - 2);
                const int off = ((yy & (HH - 1)) << 7) + xoff[k % 3];
                const float m = (xm[k % 3] && ((unsigned)yy < (unsigned)HH)) ? 1.f : 0.f;
                const f32x4 wg = __builtin_amdgcn_mfma_f32_16x16x32_f16(af[k], tnf, zc, 0, 0, 0);
                acc[0] = fmaf(wg[0], xp[off + 0 * HWSZ] * m, acc[0]);
                acc[1] = fmaf(wg[1], xp[off + 1 * HWSZ] * m, acc[1]);
                acc[2] = fmaf(wg[2], xp[off + 2 * HWSZ] * m, acc[2]);
                acc[3] = fmaf(wg[3], xp[off + 3 * HWSZ] * m, acc[3]);
            }
        }

        float* o = op + pix;
        __builtin_nontemporal_store(acc[0], o + 0 * HWSZ);
        __builtin_nontemporal_store(acc[1], o + 1 * HWSZ);
        __builtin_nontemporal_store(acc[2], o + 2 * HWSZ);
        __builtin_nontemporal_store(acc[3], o + 3 * HWSZ);

        tnf = tnf_nxt;
        if (lg == 2) tnf[0] = (_Float16)1.f;   // restore bias lane (reg move)
    }
}

extern "C" void kernel_launch(void* const* d_in, const int* in_sizes, int n_in,
                              void* d_out, int out_size, void* d_ws, size_t ws_size,
                              hipStream_t stream) {
    const float* x     = (const float*)d_in[0];
    const float* w1    = (const float*)d_in[1];
    const float* gamma = (const float*)d_in[2];
    const float* beta  = (const float*)d_in[3];
    const float* w2    = (const float*)d_in[4];
    const float* b2    = (const float*)d_in[5];
    float* out = (float*)d_out;
    float* ws  = (float*)d_ws;

    void* args[7] = {(void*)&x, (void*)&w1, (void*)&w2, (void*)&b2,
                     (void*)&gamma, (void*)&beta, (void*)&ws};
    hipLaunchCooperativeKernel((const void*)k_pre, dim3(530), dim3(256),
                               args, 0, stream);

    k_main<<<4096, 256, 0, stream>>>(x, ws, out);
}

// Round 19
// 71.415 us; speedup vs baseline: 1.6555x; 1.6376x over previous
//
#include <hip/hip_runtime.h>

// Problem constants
#define BB   8
#define CC   128
#define CR   16      // reduced channels = 128/8
#define HH   128
#define WW   128
#define HWSZ 16384   // 128*128
#define K2   9
#define NFRAG 72     // 8 ctiles * 9 taps

typedef _Float16 f16x8 __attribute__((ext_vector_type(8)));
typedef float    f32x4 __attribute__((ext_vector_type(4)));

// ws layout (float slots):
//   part    : [0, +16384)            per-tile {sum,sumsq} partials (f32)
//   traw_lo : [16384, +524288)       raw t ch 0..7,  f16x8 per pixel (b,hw)
//   traw_hi : [540672, +524288)      raw t ch 8..15
//   stats   : [1064960, +256)        per b: sc[16], sh[16]
//   afrag   : [1065216, +18432)      A fragments f16x8/lane (bias at kk=16)
#define WS_PART   0
#define WS_TRAWLO 16384
#define WS_TRAWHI 540672
#define WS_STATS  1064960
#define WS_AFRAG  1065216

// Fused: blocks 0..511 = conv1 (+ per-tile partial stats); 512..529 = w2/b2 prep.
__global__ __launch_bounds__(256) void k_conv1(const float* __restrict__ x,
                                               const float* __restrict__ w1,
                                               const float* __restrict__ w2,
                                               const float* __restrict__ b2,
                                               float* __restrict__ ws) {
    const int bid = blockIdx.x;
    const int tid = threadIdx.x;

    if (bid >= 512) {   // ---- prep branch ----
        const int id = (bid - 512) * 256 + tid;
        if (id >= NFRAG * 64) return;
        const int lane = id & 63;
        const int frag = id >> 6;           // ct*9 + k
        const int ct = frag / 9, k = frag - ct * 9;
        const int row = lane & 15, lg = lane >> 4;
        f16x8 v;
#pragma unroll
        for (int i = 0; i < 8; ++i) {
            const int kk = lg * 8 + i;
            float w = 0.f;
            if (kk < CR)        w = w2[(size_t)((ct * 16 + row) * K2 + k) * CR + kk];
            else if (kk == CR)  w = b2[(ct * 16 + row) * K2 + k];
            v[i] = (_Float16)w;
        }
        ((f16x8*)(ws + WS_AFRAG))[frag * 64 + lane] = v;
        return;
    }

    // ---- conv1 branch ----
    const int tile = bid & 63;
    const int b    = bid >> 6;
    const int pix  = tile * 256 + tid;

    // w1 staged TRANSPOSED: w1s[cin*16 + o] -> per-cin weights are f32x4 quads
    __shared__ float w1s[CR * CC];   // 8 KB
    for (int i = tid; i < CR * CC; i += 256)
        w1s[i] = w1[(i & 15) * CC + (i >> 4)];
    __syncthreads();

    const float* xb = x + (size_t)b * CC * HWSZ + pix;
    float acc[CR];
#pragma unroll
    for (int o = 0; o < CR; ++o) acc[o] = 0.f;

#pragma unroll 1
    for (int c0 = 0; c0 < CC; c0 += 16) {
        float xv[16];
#pragma unroll
        for (int u = 0; u < 16; ++u)
            xv[u] = xb[(size_t)(c0 + u) * HWSZ];
#pragma unroll
        for (int u = 0; u < 16; ++u) {
            const f32x4* wv4 = (const f32x4*)&w1s[(c0 + u) * CR];  // wave-uniform
            const f32x4 wa = wv4[0], wb = wv4[1], wc = wv4[2], wd = wv4[3];
#pragma unroll
            for (int j = 0; j < 4; ++j) {
                acc[j]      = fmaf(wa[j], xv[u], acc[j]);
                acc[4 + j]  = fmaf(wb[j], xv[u], acc[4 + j]);
                acc[8 + j]  = fmaf(wc[j], xv[u], acc[8 + j]);
                acc[12 + j] = fmaf(wd[j], xv[u], acc[12 + j]);
            }
        }
    }

    // raw t as packed f16, two coalesced planes
    {
        f16x8 lo, hi;
#pragma unroll
        for (int i = 0; i < 8; ++i) {
            lo[i] = (_Float16)acc[i];
            hi[i] = (_Float16)acc[i + 8];
        }
        ((f16x8*)(ws + WS_TRAWLO))[(size_t)b * HWSZ + pix] = lo;
        ((f16x8*)(ws + WS_TRAWHI))[(size_t)b * HWSZ + pix] = hi;
    }

    __shared__ float red[4][CR][2];
    const int lane = tid & 63;
    const int wv   = tid >> 6;
#pragma unroll
    for (int o = 0; o < CR; ++o) {
        float s = acc[o];
        float q = s * s;
#pragma unroll
        for (int off = 32; off > 0; off >>= 1) {
            s += __shfl_down(s, off, 64);
            q += __shfl_down(q, off, 64);
        }
        if (lane == 0) { red[wv][o][0] = s; red[wv][o][1] = q; }
    }
    __syncthreads();
    if (tid < CR) {
        const int o = tid;
        float s = red[0][o][0] + red[1][o][0] + red[2][o][0] + red[3][o][0];
        float q = red[0][o][1] + red[1][o][1] + red[2][o][1] + red[3][o][1];
        const int blk = b * 64 + tile;
        ws[WS_PART + blk * 32 + o * 2 + 0] = s;
        ws[WS_PART + blk * 32 + o * 2 + 1] = q;
    }
}

// grid = 128 blocks (b*16+o), block = 64; wave-reduce over 64 tiles.
// Writes per-b {sc[16], sh[16]} (f32).
__global__ void k_stats(const float* __restrict__ ws_in,
                        const float* __restrict__ gamma,
                        const float* __restrict__ beta,
                        float* __restrict__ ws_out) {
    const int b   = blockIdx.x >> 4;
    const int o   = blockIdx.x & 15;
    const int tle = threadIdx.x;            // 0..63
    const float* part = ws_in + WS_PART;
    float s = part[(b * 64 + tle) * 32 + o * 2 + 0];
    float q = part[(b * 64 + tle) * 32 + o * 2 + 1];
#pragma unroll
    for (int off = 32; off > 0; off >>= 1) {
        s += __shfl_down(s, off, 64);
        q += __shfl_down(q, off, 64);
    }
    if (tle == 0) {
        const float mean = s * (1.f / (float)HWSZ);
        const float var  = q * (1.f / (float)HWSZ) - mean * mean;
        const float rstd = rsqrtf(var + 1e-5f);
        const float sc   = gamma[o] * rstd;
        ws_out[WS_STATS + b * 32 + o]      = sc;
        ws_out[WS_STATS + b * 32 + 16 + o] = beta[o] - mean * sc;
    }
}

// Fused MFMA weight-gen + dilated 3x3 involution apply — r12 body (best
// measured 43.3-43.6 us) with InstanceNorm affine+ReLU folded in: B-frag is
// built from RAW t planes via packed-f16 max(raw*sc+sh, 0) (sc/sh hoisted
// once per wave, +8 VGPR). k_norm kernel eliminated entirely.
// grid = 4096, XCD-chunked swizzle, y innermost for L2 tap locality.
__global__ __launch_bounds__(256) void k_main(const float* __restrict__ x,
                                              const float* __restrict__ ws,
                                              float* __restrict__ out) {
    const int bid = blockIdx.x;                 // 0..4095
    const int w   = (bid & 7) * 512 + (bid >> 3);
    const int y4    = w & 31;
    const int xhalf = (w >> 5) & 1;
    const int ct    = (w >> 6) & 7;
    const int b     = w >> 9;

    const int tid  = threadIdx.x;
    const int wv   = tid >> 6;
    const int lane = tid & 63;
    const int lg   = lane >> 4;           // 0..3
    const int ln   = lane & 15;
    const int y    = y4 * 4 + wv;

    // RAW t plane for this lane group (lg0 -> lo, lg1 -> hi)
    const f16x8* tp = (const f16x8*)(ws + (lg == 1 ? WS_TRAWHI : WS_TRAWLO))
                      + ((size_t)b << 14);
    const int tbase = y * WW + xhalf * 64 + ln;

    // per-lane-group scale/shift as packed f16 (hoisted, wave-lifetime)
    const float* stp = ws + WS_STATS + b * 32 + (lg == 1 ? 8 : 0);
    f16x8 scv, shv;
#pragma unroll
    for (int i = 0; i < 8; ++i) {
        scv[i] = (_Float16)stp[i];
        shv[i] = (_Float16)stp[16 + i];
    }

    // issue first raw load before the af loads so it overlaps them
    f16x8 raw = {}, raw_nxt = {};
    if (lg < 2) raw = tp[tbase];

    // ---- 9 A-fragments into registers (L2-hot ws reads, once per wave) ----
    const f16x8* afr = (const f16x8*)(ws + WS_AFRAG) + (size_t)ct * K2 * 64 + lane;
    f16x8 af[K2];
#pragma unroll
    for (int k = 0; k < K2; ++k) af[k] = afr[k * 64];

    const int crow = lg * 4;
    const int cb   = ct * 16 + crow;
    const float* xp = x   + ((size_t)b * CC + cb) * HWSZ;
    float*       op = out + ((size_t)b * CC + cb) * HWSZ;
    const bool yint = (y >= 2) && (y < HH - 2);
    const f32x4 zc = {0.f, 0.f, 0.f, 0.f};

#pragma unroll 1
    for (int g = 0; g < 4; ++g) {
        const int colb = xhalf * 64 + g * 16;
        const int col  = colb + ln;
        const int pix  = y * WW + col;

        // prefetch next group's raw B-data (hides L2 latency under compute)
        if (g < 3 && lg < 2)
            raw_nxt = tp[tbase + (g + 1) * 16];

        // B-fragment: affine+ReLU in packed f16 (lg<2), bias lane (lg==2)
        f16x8 tnf = {};
        if (lg < 2) {
#pragma unroll
            for (int i = 0; i < 8; ++i) {
                const _Float16 v = raw[i] * scv[i] + shv[i];
                tnf[i] = v > (_Float16)0.f ? v : (_Float16)0.f;
            }
        } else if (lg == 2) {
            tnf[0] = (_Float16)1.f;
        }

        f32x4 acc = {0.f, 0.f, 0.f, 0.f};
        const bool xint = (colb >= 2) && (colb + 17 < WW);

        if (yint && xint) {
            const float* q0 = xp + pix;
            const float* q1 = q0 + HWSZ;
            const float* q2 = q0 + 2 * HWSZ;
            const float* q3 = q0 + 3 * HWSZ;
#pragma unroll
            for (int k = 0; k < K2; ++k) {
                const int d = ((k / 3) * 2 - 2) * WW + ((k % 3) * 2 - 2);  // compile-time imm
                const f32x4 wg = __builtin_amdgcn_mfma_f32_16x16x32_f16(af[k], tnf, zc, 0, 0, 0);
                acc[0] = fmaf(wg[0], q0[d], acc[0]);
                acc[1] = fmaf(wg[1], q1[d], acc[1]);
                acc[2] = fmaf(wg[2], q2[d], acc[2]);
                acc[3] = fmaf(wg[3], q3[d], acc[3]);
            }
        } else {
            int  xoff[3];
            bool xm[3];
#pragma unroll
            for (int j = 0; j < 3; ++j) {
                const int xx = col + (j * 2 - 2);
                xm[j]   = ((unsigned)xx < (unsigned)WW);
                xoff[j] = xx & (WW - 1);
            }
#pragma unroll
            for (int k = 0; k < K2; ++k) {
                const int yy  = y + ((k / 3) * 2 - 2);
                const int off = ((yy & (HH - 1)) << 7) + xoff[k % 3];
                const float m = (xm[k % 3] && ((unsigned)yy < (unsigned)HH)) ? 1.f : 0.f;
                const f32x4 wg = __builtin_amdgcn_mfma_f32_16x16x32_f16(af[k], tnf, zc, 0, 0, 0);
                acc[0] = fmaf(wg[0], xp[off + 0 * HWSZ] * m, acc[0]);
                acc[1] = fmaf(wg[1], xp[off + 1 * HWSZ] * m, acc[1]);
                acc[2] = fmaf(wg[2], xp[off + 2 * HWSZ] * m, acc[2]);
                acc[3] = fmaf(wg[3], xp[off + 3 * HWSZ] * m, acc[3]);
            }
        }

        float* o = op + pix;
        __builtin_nontemporal_store(acc[0], o + 0 * HWSZ);
        __builtin_nontemporal_store(acc[1], o + 1 * HWSZ);
        __builtin_nontemporal_store(acc[2], o + 2 * HWSZ);
        __builtin_nontemporal_store(acc[3], o + 3 * HWSZ);

        raw = raw_nxt;
    }
}

extern "C" void kernel_launch(void* const* d_in, const int* in_sizes, int n_in,
                              void* d_out, int out_size, void* d_ws, size_t ws_size,
                              hipStream_t stream) {
    const float* x     = (const float*)d_in[0];
    const float* w1    = (const float*)d_in[1];
    const float* gamma = (const float*)d_in[2];
    const float* beta  = (const float*)d_in[3];
    const float* w2    = (const float*)d_in[4];
    const float* b2    = (const float*)d_in[5];
    float* out = (float*)d_out;
    float* ws  = (float*)d_ws;

    k_conv1<<<530, 256, 0, stream>>>(x, w1, w2, b2, ws);

    k_stats<<<128, 64, 0, stream>>>(ws, gamma, beta, ws);

    k_main<<<4096, 256, 0, stream>>>(x, ws, out);
}

// Round 20
// 71.058 us; speedup vs baseline: 1.6638x; 1.0050x over previous
//
#include <hip/hip_runtime.h>

// Problem constants
#define BB   8
#define CC   128
#define CR   16      // reduced channels = 128/8
#define HH   128
#define WW   128
#define HWSZ 16384   // 128*128
#define K2   9
#define NFRAG 72     // 8 ctiles * 9 taps

typedef _Float16 f16x8 __attribute__((ext_vector_type(8)));
typedef float    f32x4 __attribute__((ext_vector_type(4)));

// ws layout (float slots):
//   part    : [0, +16384)            per-tile {sum,sumsq} partials (f32)
//   traw_lo : [16384, +524288)       raw t ch 0..7,  f16x8 per pixel (b,hw)
//   traw_hi : [540672, +524288)      raw t ch 8..15
//   tn_lo   : [1064960, +524288)     normalized t ch 0..7
//   tn_hi   : [1589248, +524288)     normalized t ch 8..15
//   afrag   : [2113536, +18432)      A fragments f16x8/lane (bias at kk=16)
#define WS_PART   0
#define WS_TRAWLO 16384
#define WS_TRAWHI 540672
#define WS_TNLO   1064960
#define WS_TNHI   1589248
#define WS_AFRAG  2113536

// Fused: blocks 0..511 = conv1 (+ per-tile partial stats); 512..529 = w2/b2 prep.
__global__ __launch_bounds__(256) void k_conv1(const float* __restrict__ x,
                                               const float* __restrict__ w1,
                                               const float* __restrict__ w2,
                                               const float* __restrict__ b2,
                                               float* __restrict__ ws) {
    const int bid = blockIdx.x;
    const int tid = threadIdx.x;

    if (bid >= 512) {   // ---- prep branch ----
        const int id = (bid - 512) * 256 + tid;
        if (id >= NFRAG * 64) return;
        const int lane = id & 63;
        const int frag = id >> 6;           // ct*9 + k
        const int ct = frag / 9, k = frag - ct * 9;
        const int row = lane & 15, lg = lane >> 4;
        f16x8 v;
#pragma unroll
        for (int i = 0; i < 8; ++i) {
            const int kk = lg * 8 + i;
            float w = 0.f;
            if (kk < CR)        w = w2[(size_t)((ct * 16 + row) * K2 + k) * CR + kk];
            else if (kk == CR)  w = b2[(ct * 16 + row) * K2 + k];
            v[i] = (_Float16)w;
        }
        ((f16x8*)(ws + WS_AFRAG))[frag * 64 + lane] = v;
        return;
    }

    // ---- conv1 branch (r13 version: x16 unroll, transposed w1s) ----
    const int tile = bid & 63;
    const int b    = bid >> 6;
    const int pix  = tile * 256 + tid;

    // w1 staged TRANSPOSED: w1s[cin*16 + o] -> per-cin weights are f32x4 quads
    __shared__ float w1s[CR * CC];   // 8 KB
    for (int i = tid; i < CR * CC; i += 256)
        w1s[i] = w1[(i & 15) * CC + (i >> 4)];
    __syncthreads();

    const float* xb = x + (size_t)b * CC * HWSZ + pix;
    float acc[CR];
#pragma unroll
    for (int o = 0; o < CR; ++o) acc[o] = 0.f;

#pragma unroll 1
    for (int c0 = 0; c0 < CC; c0 += 16) {
        float xv[16];
#pragma unroll
        for (int u = 0; u < 16; ++u)
            xv[u] = xb[(size_t)(c0 + u) * HWSZ];
#pragma unroll
        for (int u = 0; u < 16; ++u) {
            const f32x4* wv4 = (const f32x4*)&w1s[(c0 + u) * CR];  // wave-uniform
            const f32x4 wa = wv4[0], wb = wv4[1], wc = wv4[2], wd = wv4[3];
#pragma unroll
            for (int j = 0; j < 4; ++j) {
                acc[j]      = fmaf(wa[j], xv[u], acc[j]);
                acc[4 + j]  = fmaf(wb[j], xv[u], acc[4 + j]);
                acc[8 + j]  = fmaf(wc[j], xv[u], acc[8 + j]);
                acc[12 + j] = fmaf(wd[j], xv[u], acc[12 + j]);
            }
        }
    }

    // raw t as packed f16, two coalesced planes
    {
        f16x8 lo, hi;
#pragma unroll
        for (int i = 0; i < 8; ++i) {
            lo[i] = (_Float16)acc[i];
            hi[i] = (_Float16)acc[i + 8];
        }
        ((f16x8*)(ws + WS_TRAWLO))[(size_t)b * HWSZ + pix] = lo;
        ((f16x8*)(ws + WS_TRAWHI))[(size_t)b * HWSZ + pix] = hi;
    }

    __shared__ float red[4][CR][2];
    const int lane = tid & 63;
    const int wv   = tid >> 6;
#pragma unroll
    for (int o = 0; o < CR; ++o) {
        float s = acc[o];
        float q = s * s;
#pragma unroll
        for (int off = 32; off > 0; off >>= 1) {
            s += __shfl_down(s, off, 64);
            q += __shfl_down(q, off, 64);
        }
        if (lane == 0) { red[wv][o][0] = s; red[wv][o][1] = q; }
    }
    __syncthreads();
    if (tid < CR) {
        const int o = tid;
        float s = red[0][o][0] + red[1][o][0] + red[2][o][0] + red[3][o][0];
        float q = red[0][o][1] + red[1][o][1] + red[2][o][1] + red[3][o][1];
        const int blk = b * 64 + tile;
        ws[WS_PART + blk * 32 + o * 2 + 0] = s;
        ws[WS_PART + blk * 32 + o * 2 + 1] = q;
    }
}

// Normalize raw f16 t -> tn planes; stats folded in (per-block re-reduce of
// this batch's 2 KB of `part` from L2).
__global__ __launch_bounds__(256) void k_norm(const float* __restrict__ ws_in,
                                              const float* __restrict__ gamma,
                                              const float* __restrict__ beta,
                                              float* __restrict__ ws_out) {
    const int tid = threadIdx.x;
    const int p   = blockIdx.x * 256 + tid;   // 0..131071
    const int b   = p >> 14;

    const float* part = ws_in + WS_PART;

    __shared__ float sts[CR][2];
    {
        const int o  = tid >> 4;
        const int t4 = tid & 15;
        float s = 0.f, q = 0.f;
        if (o < CR) {
#pragma unroll
            for (int j = 0; j < 4; ++j) {
                const int blk = b * 64 + t4 + j * 16;
                s += part[blk * 32 + o * 2 + 0];
                q += part[blk * 32 + o * 2 + 1];
            }
#pragma unroll
            for (int off = 8; off > 0; off >>= 1) {
                s += __shfl_down(s, off, 16);
                q += __shfl_down(q, off, 16);
            }
            if (t4 == 0) {
                const float mean = s * (1.f / (float)HWSZ);
                const float var  = q * (1.f / (float)HWSZ) - mean * mean;
                const float rstd = rsqrtf(var + 1e-5f);
                const float sc   = gamma[o] * rstd;
                sts[o][0] = sc;
                sts[o][1] = beta[o] - mean * sc;
            }
        }
    }
    __syncthreads();

    const f16x8 lo = ((const f16x8*)(ws_in + WS_TRAWLO))[p];
    const f16x8 hi = ((const f16x8*)(ws_in + WS_TRAWHI))[p];
    f16x8 nlo, nhi;
#pragma unroll
    for (int i = 0; i < 8; ++i) {
        float v0 = fmaf((float)lo[i], sts[i][0],     sts[i][1]);
        float v1 = fmaf((float)hi[i], sts[i + 8][0], sts[i + 8][1]);
        nlo[i] = (_Float16)(v0 > 0.f ? v0 : 0.f);
        nhi[i] = (_Float16)(v1 > 0.f ? v1 : 0.f);
    }
    ((f16x8*)(ws_out + WS_TNLO))[p] = nlo;
    ((f16x8*)(ws_out + WS_TNHI))[p] = nhi;
}

// Fused MFMA weight-gen + dilated 3x3 involution apply — r12 body (best
// measured 43.3-43.6 us) with ONE change: g-loop unrolled x2 so the
// scheduler can interleave two independent pixel-group streams (2x per-wave
// loads in flight). Rotation prefetch kept. NT stores for out.
// grid = 4096, XCD-chunked swizzle, y innermost for L2 tap locality.
__global__ __launch_bounds__(256) void k_main(const float* __restrict__ x,
                                              const float* __restrict__ ws,
                                              float* __restrict__ out) {
    const int bid = blockIdx.x;                 // 0..4095
    const int w   = (bid & 7) * 512 + (bid >> 3);
    const int y4    = w & 31;
    const int xhalf = (w >> 5) & 1;
    const int ct    = (w >> 6) & 7;
    const int b     = w >> 9;

    const int tid  = threadIdx.x;
    const int wv   = tid >> 6;
    const int lane = tid & 63;
    const int lg   = lane >> 4;           // 0..3
    const int ln   = lane & 15;
    const int y    = y4 * 4 + wv;

    // B-fragment plane for this lane group (lg0 -> lo, lg1 -> hi)
    const f16x8* tp = (const f16x8*)(ws + (lg == 1 ? WS_TNHI : WS_TNLO))
                      + ((size_t)b << 14);
    const int tbase = y * WW + xhalf * 64 + ln;

    // issue first tnf load before the af loads so it overlaps them
    f16x8 tnf = {}, tnf_nxt = {};
    if (lg < 2)  tnf = tp[tbase];
    if (lg == 2) tnf[0] = (_Float16)1.f;

    // ---- 9 A-fragments into registers (L2-hot ws reads, once per wave) ----
    const f16x8* afr = (const f16x8*)(ws + WS_AFRAG) + (size_t)ct * K2 * 64 + lane;
    f16x8 af[K2];
#pragma unroll
    for (int k = 0; k < K2; ++k) af[k] = afr[k * 64];

    const int crow = lg * 4;
    const int cb   = ct * 16 + crow;
    const float* xp = x   + ((size_t)b * CC + cb) * HWSZ;
    float*       op = out + ((size_t)b * CC + cb) * HWSZ;
    const bool yint = (y >= 2) && (y < HH - 2);
    const f32x4 zc = {0.f, 0.f, 0.f, 0.f};

#pragma unroll 2
    for (int g = 0; g < 4; ++g) {
        const int colb = xhalf * 64 + g * 16;
        const int col  = colb + ln;
        const int pix  = y * WW + col;

        // prefetch next group's B-fragment (hides L2 latency under compute)
        if (g < 3 && lg < 2)
            tnf_nxt = tp[tbase + (g + 1) * 16];

        f32x4 acc = {0.f, 0.f, 0.f, 0.f};
        const bool xint = (colb >= 2) && (colb + 17 < WW);

        if (yint && xint) {
            const float* q0 = xp + pix;
            const float* q1 = q0 + HWSZ;
            const float* q2 = q0 + 2 * HWSZ;
            const float* q3 = q0 + 3 * HWSZ;
#pragma unroll
            for (int k = 0; k < K2; ++k) {
                const int d = ((k / 3) * 2 - 2) * WW + ((k % 3) * 2 - 2);  // compile-time imm
                const f32x4 wg = __builtin_amdgcn_mfma_f32_16x16x32_f16(af[k], tnf, zc, 0, 0, 0);
                acc[0] = fmaf(wg[0], q0[d], acc[0]);
                acc[1] = fmaf(wg[1], q1[d], acc[1]);
                acc[2] = fmaf(wg[2], q2[d], acc[2]);
                acc[3] = fmaf(wg[3], q3[d], acc[3]);
            }
        } else {
            int  xoff[3];
            bool xm[3];
#pragma unroll
            for (int j = 0; j < 3; ++j) {
                const int xx = col + (j * 2 - 2);
                xm[j]   = ((unsigned)xx < (unsigned)WW);
                xoff[j] = xx & (WW - 1);
            }
#pragma unroll
            for (int k = 0; k < K2; ++k) {
                const int yy  = y + ((k / 3) * 2 - 2);
                const int off = ((yy & (HH - 1)) << 7) + xoff[k % 3];
                const float m = (xm[k % 3] && ((unsigned)yy < (unsigned)HH)) ? 1.f : 0.f;
                const f32x4 wg = __builtin_amdgcn_mfma_f32_16x16x32_f16(af[k], tnf, zc, 0, 0, 0);
                acc[0] = fmaf(wg[0], xp[off + 0 * HWSZ] * m, acc[0]);
                acc[1] = fmaf(wg[1], xp[off + 1 * HWSZ] * m, acc[1]);
                acc[2] = fmaf(wg[2], xp[off + 2 * HWSZ] * m, acc[2]);
                acc[3] = fmaf(wg[3], xp[off + 3 * HWSZ] * m, acc[3]);
            }
        }

        float* o = op + pix;
        __builtin_nontemporal_store(acc[0], o + 0 * HWSZ);
        __builtin_nontemporal_store(acc[1], o + 1 * HWSZ);
        __builtin_nontemporal_store(acc[2], o + 2 * HWSZ);
        __builtin_nontemporal_store(acc[3], o + 3 * HWSZ);

        tnf = tnf_nxt;
        if (lg == 2) tnf[0] = (_Float16)1.f;   // restore bias lane (reg move)
    }
}

extern "C" void kernel_launch(void* const* d_in, const int* in_sizes, int n_in,
                              void* d_out, int out_size, void* d_ws, size_t ws_size,
                              hipStream_t stream) {
    const float* x     = (const float*)d_in[0];
    const float* w1    = (const float*)d_in[1];
    const float* gamma = (const float*)d_in[2];
    const float* beta  = (const float*)d_in[3];
    const float* w2    = (const float*)d_in[4];
    const float* b2    = (const float*)d_in[5];
    float* out = (float*)d_out;
    float* ws  = (float*)d_ws;

    k_conv1<<<530, 256, 0, stream>>>(x, w1, w2, b2, ws);

    k_norm<<<512, 256, 0, stream>>>(ws, gamma, beta, ws);

    k_main<<<4096, 256, 0, stream>>>(x, ws, out);
}

// Round 21
// 68.737 us; speedup vs baseline: 1.7200x; 1.0338x over previous
//
#include <hip/hip_runtime.h>

// Problem constants
#define BB   8
#define CC   128
#define CR   16      // reduced channels = 128/8
#define HH   128
#define WW   128
#define HWSZ 16384   // 128*128
#define K2   9
#define NFRAG 72     // 8 ctiles * 9 taps

typedef _Float16 f16x8 __attribute__((ext_vector_type(8)));
typedef float    f32x4 __attribute__((ext_vector_type(4)));

// ws layout (float slots):
//   part    : [0, +16384)            per-tile {sum,sumsq} partials (f32)
//   traw_lo : [16384, +524288)       raw t ch 0..7,  f16x8 per pixel (b,hw)
//   traw_hi : [540672, +524288)      raw t ch 8..15
//   tn_lo   : [1064960, +524288)     normalized t ch 0..7
//   tn_hi   : [1589248, +524288)     normalized t ch 8..15
//   afrag   : [2113536, +18432)      A fragments f16x8/lane (bias at kk=16)
#define WS_PART   0
#define WS_TRAWLO 16384
#define WS_TRAWHI 540672
#define WS_TNLO   1064960
#define WS_TNHI   1589248
#define WS_AFRAG  2113536

// Fused: blocks 0..511 = conv1 (+ per-tile partial stats); 512..529 = w2/b2 prep.
__global__ __launch_bounds__(256) void k_conv1(const float* __restrict__ x,
                                               const float* __restrict__ w1,
                                               const float* __restrict__ w2,
                                               const float* __restrict__ b2,
                                               float* __restrict__ ws) {
    const int bid = blockIdx.x;
    const int tid = threadIdx.x;

    if (bid >= 512) {   // ---- prep branch ----
        const int id = (bid - 512) * 256 + tid;
        if (id >= NFRAG * 64) return;
        const int lane = id & 63;
        const int frag = id >> 6;           // ct*9 + k
        const int ct = frag / 9, k = frag - ct * 9;
        const int row = lane & 15, lg = lane >> 4;
        f16x8 v;
#pragma unroll
        for (int i = 0; i < 8; ++i) {
            const int kk = lg * 8 + i;
            float w = 0.f;
            if (kk < CR)        w = w2[(size_t)((ct * 16 + row) * K2 + k) * CR + kk];
            else if (kk == CR)  w = b2[(ct * 16 + row) * K2 + k];
            v[i] = (_Float16)w;
        }
        ((f16x8*)(ws + WS_AFRAG))[frag * 64 + lane] = v;
        return;
    }

    // ---- conv1 branch (x16 unroll, transposed w1s) ----
    const int tile = bid & 63;
    const int b    = bid >> 6;
    const int pix  = tile * 256 + tid;

    __shared__ float w1s[CR * CC];   // 8 KB
    for (int i = tid; i < CR * CC; i += 256)
        w1s[i] = w1[(i & 15) * CC + (i >> 4)];
    __syncthreads();

    const float* xb = x + (size_t)b * CC * HWSZ + pix;
    float acc[CR];
#pragma unroll
    for (int o = 0; o < CR; ++o) acc[o] = 0.f;

#pragma unroll 1
    for (int c0 = 0; c0 < CC; c0 += 16) {
        float xv[16];
#pragma unroll
        for (int u = 0; u < 16; ++u)
            xv[u] = xb[(size_t)(c0 + u) * HWSZ];
#pragma unroll
        for (int u = 0; u < 16; ++u) {
            const f32x4* wv4 = (const f32x4*)&w1s[(c0 + u) * CR];  // wave-uniform
            const f32x4 wa = wv4[0], wb = wv4[1], wc = wv4[2], wd = wv4[3];
#pragma unroll
            for (int j = 0; j < 4; ++j) {
                acc[j]      = fmaf(wa[j], xv[u], acc[j]);
                acc[4 + j]  = fmaf(wb[j], xv[u], acc[4 + j]);
                acc[8 + j]  = fmaf(wc[j], xv[u], acc[8 + j]);
                acc[12 + j] = fmaf(wd[j], xv[u], acc[12 + j]);
            }
        }
    }

    // raw t as packed f16, two coalesced planes
    {
        f16x8 lo, hi;
#pragma unroll
        for (int i = 0; i < 8; ++i) {
            lo[i] = (_Float16)acc[i];
            hi[i] = (_Float16)acc[i + 8];
        }
        ((f16x8*)(ws + WS_TRAWLO))[(size_t)b * HWSZ + pix] = lo;
        ((f16x8*)(ws + WS_TRAWHI))[(size_t)b * HWSZ + pix] = hi;
    }

    __shared__ float red[4][CR][2];
    const int lane = tid & 63;
    const int wv   = tid >> 6;
#pragma unroll
    for (int o = 0; o < CR; ++o) {
        float s = acc[o];
        float q = s * s;
#pragma unroll
        for (int off = 32; off > 0; off >>= 1) {
            s += __shfl_down(s, off, 64);
            q += __shfl_down(q, off, 64);
        }
        if (lane == 0) { red[wv][o][0] = s; red[wv][o][1] = q; }
    }
    __syncthreads();
    if (tid < CR) {
        const int o = tid;
        float s = red[0][o][0] + red[1][o][0] + red[2][o][0] + red[3][o][0];
        float q = red[0][o][1] + red[1][o][1] + red[2][o][1] + red[3][o][1];
        const int blk = b * 64 + tile;
        ws[WS_PART + blk * 32 + o * 2 + 0] = s;
        ws[WS_PART + blk * 32 + o * 2 + 1] = q;
    }
}

// Normalize raw f16 t -> tn planes; stats folded in (per-block re-reduce of
// this batch's 2 KB of `part` from L2).
__global__ __launch_bounds__(256) void k_norm(const float* __restrict__ ws_in,
                                              const float* __restrict__ gamma,
                                              const float* __restrict__ beta,
                                              float* __restrict__ ws_out) {
    const int tid = threadIdx.x;
    const int p   = blockIdx.x * 256 + tid;   // 0..131071
    const int b   = p >> 14;

    const float* part = ws_in + WS_PART;

    __shared__ float sts[CR][2];
    {
        const int o  = tid >> 4;
        const int t4 = tid & 15;
        float s = 0.f, q = 0.f;
        if (o < CR) {
#pragma unroll
            for (int j = 0; j < 4; ++j) {
                const int blk = b * 64 + t4 + j * 16;
                s += part[blk * 32 + o * 2 + 0];
                q += part[blk * 32 + o * 2 + 1];
            }
#pragma unroll
            for (int off = 8; off > 0; off >>= 1) {
                s += __shfl_down(s, off, 16);
                q += __shfl_down(q, off, 16);
            }
            if (t4 == 0) {
                const float mean = s * (1.f / (float)HWSZ);
                const float var  = q * (1.f / (float)HWSZ) - mean * mean;
                const float rstd = rsqrtf(var + 1e-5f);
                const float sc   = gamma[o] * rstd;
                sts[o][0] = sc;
                sts[o][1] = beta[o] - mean * sc;
            }
        }
    }
    __syncthreads();

    const f16x8 lo = ((const f16x8*)(ws_in + WS_TRAWLO))[p];
    const f16x8 hi = ((const f16x8*)(ws_in + WS_TRAWHI))[p];
    f16x8 nlo, nhi;
#pragma unroll
    for (int i = 0; i < 8; ++i) {
        float v0 = fmaf((float)lo[i], sts[i][0],     sts[i][1]);
        float v1 = fmaf((float)hi[i], sts[i + 8][0], sts[i + 8][1]);
        nlo[i] = (_Float16)(v0 > 0.f ? v0 : 0.f);
        nhi[i] = (_Float16)(v1 > 0.f ? v1 : 0.f);
    }
    ((f16x8*)(ws_out + WS_TNLO))[p] = nlo;
    ((f16x8*)(ws_out + WS_TNHI))[p] = nhi;
}

// Fused MFMA weight-gen + dilated 3x3 involution apply — r12 body with the
// interior path restructured as {tnf + 36 tap loads} -> sched_barrier(0) ->
// {9 MFMA + 36 FMA}. The fence is compiler-proof (r13's hoist was silently
// re-interleaved): all 36 loads stay in flight, one L2 round-trip per group
// instead of ~9 serialized ones. NT stores; XCD-chunked swizzle, y inner.
__global__ __launch_bounds__(256) void k_main(const float* __restrict__ x,
                                              const float* __restrict__ ws,
                                              float* __restrict__ out) {
    const int bid = blockIdx.x;                 // 0..4095
    const int w   = (bid & 7) * 512 + (bid >> 3);
    const int y4    = w & 31;
    const int xhalf = (w >> 5) & 1;
    const int ct    = (w >> 6) & 7;
    const int b     = w >> 9;

    const int tid  = threadIdx.x;
    const int wv   = tid >> 6;
    const int lane = tid & 63;
    const int lg   = lane >> 4;           // 0..3
    const int ln   = lane & 15;
    const int y    = y4 * 4 + wv;

    // B-fragment plane for this lane group (lg0 -> lo, lg1 -> hi)
    const f16x8* tp = (const f16x8*)(ws + (lg == 1 ? WS_TNHI : WS_TNLO))
                      + ((size_t)b << 14);
    const int tbase = y * WW + xhalf * 64 + ln;

    // ---- 9 A-fragments into registers (L2-hot ws reads, once per wave) ----
    const f16x8* afr = (const f16x8*)(ws + WS_AFRAG) + (size_t)ct * K2 * 64 + lane;
    f16x8 af[K2];
#pragma unroll
    for (int k = 0; k < K2; ++k) af[k] = afr[k * 64];

    const int crow = lg * 4;
    const int cb   = ct * 16 + crow;
    const float* xp = x   + ((size_t)b * CC + cb) * HWSZ;
    float*       op = out + ((size_t)b * CC + cb) * HWSZ;
    const bool yint = (y >= 2) && (y < HH - 2);
    const f32x4 zc = {0.f, 0.f, 0.f, 0.f};

#pragma unroll 1
    for (int g = 0; g < 4; ++g) {
        const int colb = xhalf * 64 + g * 16;
        const int col  = colb + ln;
        const int pix  = y * WW + col;
        const bool xint = (colb >= 2) && (colb + 17 < WW);

        f32x4 acc = {0.f, 0.f, 0.f, 0.f};

        if (yint && xint) {
            // ---- issue phase: tnf + all 36 tap loads, nothing consumes ----
            f16x8 tnf = {};
            if (lg < 2)  tnf = tp[tbase + g * 16];
            if (lg == 2) tnf[0] = (_Float16)1.f;

            const float* q0 = xp + pix;
            const float* q1 = q0 + HWSZ;
            const float* q2 = q0 + 2 * HWSZ;
            const float* q3 = q0 + 3 * HWSZ;
            f32x4 pv[K2];
#pragma unroll
            for (int k = 0; k < K2; ++k) {
                const int d = ((k / 3) * 2 - 2) * WW + ((k % 3) * 2 - 2);  // compile-time imm
                pv[k][0] = q0[d];
                pv[k][1] = q1[d];
                pv[k][2] = q2[d];
                pv[k][3] = q3[d];
            }

            // compiler-proof fence: no consume may be hoisted above this line
            __builtin_amdgcn_sched_barrier(0);

            // ---- consume phase: 9 MFMA + 36 FMA ----
#pragma unroll
            for (int k = 0; k < K2; ++k) {
                const f32x4 wg = __builtin_amdgcn_mfma_f32_16x16x32_f16(af[k], tnf, zc, 0, 0, 0);
                acc[0] = fmaf(wg[0], pv[k][0], acc[0]);
                acc[1] = fmaf(wg[1], pv[k][1], acc[1]);
                acc[2] = fmaf(wg[2], pv[k][2], acc[2]);
                acc[3] = fmaf(wg[3], pv[k][3], acc[3]);
            }
        } else {
            f16x8 tnf = {};
            if (lg < 2)  tnf = tp[tbase + g * 16];
            if (lg == 2) tnf[0] = (_Float16)1.f;

            int  xoff[3];
            bool xm[3];
#pragma unroll
            for (int j = 0; j < 3; ++j) {
                const int xx = col + (j * 2 - 2);
                xm[j]   = ((unsigned)xx < (unsigned)WW);
                xoff[j] = xx & (WW - 1);
            }
#pragma unroll
            for (int k = 0; k < K2; ++k) {
                const int yy  = y + ((k / 3) * 2 - 2);
                const int off = ((yy & (HH - 1)) << 7) + xoff[k % 3];
                const float m = (xm[k % 3] && ((unsigned)yy < (unsigned)HH)) ? 1.f : 0.f;
                const f32x4 wg = __builtin_amdgcn_mfma_f32_16x16x32_f16(af[k], tnf, zc, 0, 0, 0);
                acc[0] = fmaf(wg[0], xp[off + 0 * HWSZ] * m, acc[0]);
                acc[1] = fmaf(wg[1], xp[off + 1 * HWSZ] * m, acc[1]);
                acc[2] = fmaf(wg[2], xp[off + 2 * HWSZ] * m, acc[2]);
                acc[3] = fmaf(wg[3], xp[off + 3 * HWSZ] * m, acc[3]);
            }
        }

        float* o = op + pix;
        __builtin_nontemporal_store(acc[0], o + 0 * HWSZ);
        __builtin_nontemporal_store(acc[1], o + 1 * HWSZ);
        __builtin_nontemporal_store(acc[2], o + 2 * HWSZ);
        __builtin_nontemporal_store(acc[3], o + 3 * HWSZ);
    }
}

extern "C" void kernel_launch(void* const* d_in, const int* in_sizes, int n_in,
                              void* d_out, int out_size, void* d_ws, size_t ws_size,
                              hipStream_t stream) {
    const float* x     = (const float*)d_in[0];
    const float* w1    = (const float*)d_in[1];
    const float* gamma = (const float*)d_in[2];
    const float* beta  = (const float*)d_in[3];
    const float* w2    = (const float*)d_in[4];
    const float* b2    = (const float*)d_in[5];
    float* out = (float*)d_out;
    float* ws  = (float*)d_ws;

    k_conv1<<<530, 256, 0, stream>>>(x, w1, w2, b2, ws);

    k_norm<<<512, 256, 0, stream>>>(ws, gamma, beta, ws);

    k_main<<<4096, 256, 0, stream>>>(x, ws, out);
}